// Round 7
// baseline (142.098 us; speedup 1.0000x reference)
//
#include <hip/hip_runtime.h>

typedef __attribute__((ext_vector_type(8))) short bf16x8;
typedef __attribute__((ext_vector_type(4))) float f32x4;
typedef unsigned short ushort_t;

#define NB 32
#define NA 1024
#define NATOMS (NB*NA)
#define D  384
#define H1 256
#define H2 192
#define NE 4
#define TA 32
#define NGRID 1027           // max sum of ceil(n_e/32)

__device__ __forceinline__ ushort_t f2bf(float f) {
    union { float f; unsigned u; } v; v.f = f;
    unsigned r = v.u + 0x7FFF + ((v.u >> 16) & 1);   // RNE
    return (ushort_t)(r >> 16);
}

// per-wave ballot histogram -> 4 atomics per block -> rank write
__global__ __launch_bounds__(256) void scatter_kernel(
    const int* __restrict__ species, int* __restrict__ counts, int* __restrict__ bucket)
{
    __shared__ int wcnt[4][4];
    __shared__ int wbase[4][4];
    const int t = threadIdx.x, lane = t & 63, wv = t >> 6;
    const int i = blockIdx.x * 256 + t;
    const int e = species[i];

    unsigned long long m0 = __ballot(e == 0);
    unsigned long long m1 = __ballot(e == 1);
    unsigned long long m2 = __ballot(e == 2);
    unsigned long long m3 = __ballot(e == 3);
    unsigned long long mym = (e == 0) ? m0 : (e == 1) ? m1 : (e == 2) ? m2 : m3;
    const unsigned long long lt = (lane == 63) ? 0x7FFFFFFFFFFFFFFFull
                                               : ((1ull << lane) - 1ull);
    const int rank = __popcll(mym & lt);

    if (lane == 0) {
        wcnt[wv][0] = __popcll(m0); wcnt[wv][1] = __popcll(m1);
        wcnt[wv][2] = __popcll(m2); wcnt[wv][3] = __popcll(m3);
    }
    __syncthreads();
    if (t < NE) {
        int s = t;
        int tot = wcnt[0][s] + wcnt[1][s] + wcnt[2][s] + wcnt[3][s];
        int b = atomicAdd(&counts[s], tot);
        for (int w = 0; w < 4; ++w) { wbase[w][s] = b; b += wcnt[w][s]; }
    }
    __syncthreads();
    bucket[(e << 15) + wbase[wv][e] + rank] = i;
}

// fused transpose+convert (W1 and Wh) + counts zeroing (runs BEFORE scatter)
__global__ __launch_bounds__(256) void transpose_kernel(
    const float* __restrict__ W1, const float* __restrict__ Wh,
    ushort_t* __restrict__ w1t, ushort_t* __restrict__ wht,
    int* __restrict__ counts)
{
    if (blockIdx.x == 0 && threadIdx.x < NE) counts[threadIdx.x] = 0;
    __shared__ float tile[32][33];
    const int t = threadIdx.x;
    int bid = blockIdx.x;
    const float* src; ushort_t* dst; int R, C, e, rt, ct;
    if (bid < NE * 96) {                       // W1: [384][256], 12x8 tiles
        e = bid / 96; int rem = bid % 96; rt = rem / 8; ct = rem % 8;
        src = W1; dst = w1t; R = D; C = H1;
    } else {                                   // Wh: [256][192], 8x6 tiles
        bid -= NE * 96;
        e = bid / 48; int rem = bid % 48; rt = rem / 6; ct = rem % 6;
        src = Wh; dst = wht; R = H1; C = H2;
    }
    const float* S  = src + ((size_t)e * R + rt * 32) * C + ct * 32;
    ushort_t*    Dp = dst + ((size_t)e * C + ct * 32) * R + rt * 32;
    {
        int row = t >> 3, c4 = (t & 7) * 4;
        float4 v = *(const float4*)(S + (size_t)row * C + c4);
        tile[row][c4 + 0] = v.x; tile[row][c4 + 1] = v.y;
        tile[row][c4 + 2] = v.z; tile[row][c4 + 3] = v.w;
    }
    __syncthreads();
    {
        int orow = t >> 3, k4 = (t & 7) * 4;
        ushort4 o;
        o.x = f2bf(tile[k4 + 0][orow]);
        o.y = f2bf(tile[k4 + 1][orow]);
        o.z = f2bf(tile[k4 + 2][orow]);
        o.w = f2bf(tile[k4 + 3][orow]);
        *(ushort4*)(Dp + (size_t)orow * R + k4) = o;
    }
}

// XOR-swizzled LDS: phys col = ((chunk ^ (row&7)) << 3) + (col & 7), chunk = col >> 3
__global__ __launch_bounds__(256, 4) void mlp_kernel(
    const float*    __restrict__ rep,
    const int*      __restrict__ counts,
    const int*      __restrict__ bucket,
    const ushort_t* __restrict__ w1t,      // [E][H1][D]  bf16
    const ushort_t* __restrict__ wht,      // [E][H2][H1] bf16
    const float*    __restrict__ b1,
    const float*    __restrict__ bh,
    const float*    __restrict__ W2,
    const float*    __restrict__ b2,
    float*          __restrict__ energy)
{
    const int c0 = counts[0], c1 = counts[1], c2 = counts[2], c3 = counts[3];
    const int t0 = (c0 + 31) >> 5, t1 = (c1 + 31) >> 5, t2 = (c2 + 31) >> 5;
    const int t3 = (c3 + 31) >> 5;
    int bid = blockIdx.x;
    int e, tile, n;
    if      (bid < t0)                { e = 0; tile = bid;                n = c0; }
    else if (bid < t0 + t1)           { e = 1; tile = bid - t0;           n = c1; }
    else if (bid < t0 + t1 + t2)      { e = 2; tile = bid - t0 - t1;      n = c2; }
    else if (bid < t0 + t1 + t2 + t3) { e = 3; tile = bid - t0 - t1 - t2; n = c3; }
    else return;
    const int base = tile * TA;

    const int t    = threadIdx.x;
    const int lane = t & 63;
    const int wv   = t >> 6;
    const int g    = lane >> 4;
    const int r    = lane & 15;
    const int r7   = r & 7;

    __shared__ ushort_t smem[TA * D + TA * H1];   // 40,960 B exactly
    ushort_t* Xt  = smem;                         // [32][384] swizzled
    ushort_t* H1t = smem + TA * D;                // [32][256] swizzled
    float*    eparts = (float*)smem;              // aliases Xt (dead after phase 1)

    // ---- stage all of X (32 x 384) as bf16, swizzled
    {
        const int srow = t >> 3, scs = t & 7, sswz = srow & 7;
        int ai = base + srow;
        int gs = bucket[(e << 15) + (ai < n ? ai : base)];
        const float* xp = rep + (size_t)gs * D;
        #pragma unroll
        for (int i = 0; i < 6; ++i) {
            const int cs = scs + 8 * i;
            float4 v0 = *(const float4*)(xp + cs * 8);
            float4 v1 = *(const float4*)(xp + cs * 8 + 4);
            union { bf16x8 v; ushort_t u[8]; } pk;
            pk.u[0] = f2bf(v0.x); pk.u[1] = f2bf(v0.y);
            pk.u[2] = f2bf(v0.z); pk.u[3] = f2bf(v0.w);
            pk.u[4] = f2bf(v1.x); pk.u[5] = f2bf(v1.y);
            pk.u[6] = f2bf(v1.z); pk.u[7] = f2bf(v1.w);
            *(bf16x8*)(Xt + srow * D + ((cs ^ sswz) << 3)) = pk.v;
        }
    }
    __syncthreads();

    // ---- phase 1: C1^T; A = W1 frags (global), B = X frags (LDS). NO barriers.
    const ushort_t* a1p = w1t + ((size_t)e * H1 + wv * 64 + r) * D + g * 8;

    f32x4 acc1[4][2];
    #pragma unroll
    for (int nn = 0; nn < 4; ++nn)
        #pragma unroll
        for (int m = 0; m < 2; ++m)
            acc1[nn][m] = (f32x4){0.f, 0.f, 0.f, 0.f};

    #pragma unroll 4
    for (int ks = 0; ks < 12; ++ks) {
        bf16x8 bx[2];
        #pragma unroll
        for (int m = 0; m < 2; ++m) {
            const int cs = ks * 4 + g;
            bx[m] = *(const bf16x8*)(Xt + (m * 16 + r) * D + ((cs ^ r7) << 3));
        }
        #pragma unroll
        for (int nn = 0; nn < 4; ++nn) {
            bf16x8 aw = *(const bf16x8*)(a1p + (size_t)nn * 16 * D + ks * 32);
            #pragma unroll
            for (int m = 0; m < 2; ++m)
                acc1[nn][m] = __builtin_amdgcn_mfma_f32_16x16x32_bf16(
                    aw, bx[m], acc1[nn][m], 0, 0, 0);
        }
    }

    // ---- +b1, pack to bf16, write H1t (swizzled), one barrier
    #pragma unroll
    for (int nn = 0; nn < 4; ++nn) {
        float bv[4];
        #pragma unroll
        for (int q = 0; q < 4; ++q)
            bv[q] = b1[e * H1 + wv * 64 + nn * 16 + g * 4 + q];
        #pragma unroll
        for (int m = 0; m < 2; ++m) {
            unsigned p0 = f2bf(acc1[nn][m][0] + bv[0]);
            unsigned p1 = f2bf(acc1[nn][m][1] + bv[1]);
            unsigned p2 = f2bf(acc1[nn][m][2] + bv[2]);
            unsigned p3 = f2bf(acc1[nn][m][3] + bv[3]);
            uint2 pk; pk.x = p0 | (p1 << 16); pk.y = p2 | (p3 << 16);
            const int col = wv * 64 + nn * 16 + g * 4;
            const int cs  = col >> 3;
            const int phys = (m * 16 + r) * H1 + ((cs ^ r7) << 3) + (col & 7);
            *(uint2*)(H1t + phys) = pk;
        }
    }
    __syncthreads();

    // ---- phase 2: C2^T; A = Wh frags (global), B = H1 frags (LDS). NO barriers.
    const ushort_t* a2p = wht + ((size_t)e * H2 + wv * 48 + r) * H1 + g * 8;

    f32x4 acc2[3][2];
    #pragma unroll
    for (int nn = 0; nn < 3; ++nn)
        #pragma unroll
        for (int m = 0; m < 2; ++m)
            acc2[nn][m] = (f32x4){0.f, 0.f, 0.f, 0.f};

    #pragma unroll 4
    for (int ks = 0; ks < 8; ++ks) {
        bf16x8 bx[2];
        #pragma unroll
        for (int m = 0; m < 2; ++m) {
            const int cs = ks * 4 + g;
            bx[m] = *(const bf16x8*)(H1t + (m * 16 + r) * H1 + ((cs ^ r7) << 3));
        }
        #pragma unroll
        for (int nn = 0; nn < 3; ++nn) {
            bf16x8 aw = *(const bf16x8*)(a2p + (size_t)nn * 16 * H1 + ks * 32);
            #pragma unroll
            for (int m = 0; m < 2; ++m)
                acc2[nn][m] = __builtin_amdgcn_mfma_f32_16x16x32_bf16(
                    aw, bx[m], acc2[nn][m], 0, 0, 0);
        }
    }

    // ---- epilogue: relu(C2^T+bh)·W2, reduce 48 h2 rows/wave, combine via eparts
    float s2[2] = {0.f, 0.f};
    #pragma unroll
    for (int nn = 0; nn < 3; ++nn) {
        float bhv[4], w2v[4];
        #pragma unroll
        for (int q = 0; q < 4; ++q) {
            int h2i = e * H2 + wv * 48 + nn * 16 + g * 4 + q;
            bhv[q] = bh[h2i];
            w2v[q] = W2[h2i];
        }
        #pragma unroll
        for (int m = 0; m < 2; ++m)
            #pragma unroll
            for (int q = 0; q < 4; ++q) {
                float z = acc2[nn][m][q] + bhv[q];
                z = fmaxf(z, 0.f);
                s2[m] += z * w2v[q];
            }
    }
    #pragma unroll
    for (int m = 0; m < 2; ++m) {
        float s = s2[m];
        s += __shfl_xor(s, 16, 64);
        s += __shfl_xor(s, 32, 64);
        if (lane < 16) eparts[wv * TA + m * 16 + r] = s;
    }
    __syncthreads();
    if (t < TA) {
        int ai = base + t;
        if (ai < n) {
            int gi = bucket[(e << 15) + ai];
            energy[gi] = eparts[t] + eparts[TA + t] + eparts[2 * TA + t]
                       + eparts[3 * TA + t] + b2[e];
        }
    }
}

__global__ void reduce_kernel(const float* __restrict__ energy, float* __restrict__ out) {
    const int b = blockIdx.x, t = threadIdx.x;
    float s = 0.f;
    for (int i = t; i < NA; i += 256) s += energy[b * NA + i];
    for (int off = 32; off > 0; off >>= 1) s += __shfl_down(s, off, 64);
    __shared__ float ws[4];
    if ((t & 63) == 0) ws[t >> 6] = s;
    __syncthreads();
    if (t == 0) out[b] = ws[0] + ws[1] + ws[2] + ws[3];
}

extern "C" void kernel_launch(void* const* d_in, const int* in_sizes, int n_in,
                              void* d_out, int out_size, void* d_ws, size_t ws_size,
                              hipStream_t stream) {
    const float* rep     = (const float*)d_in[0];
    const int*   species = (const int*)  d_in[1];
    const float* W1      = (const float*)d_in[2];
    const float* b1      = (const float*)d_in[3];
    const float* Wh      = (const float*)d_in[4];
    const float* bh      = (const float*)d_in[5];
    const float* W2      = (const float*)d_in[6];
    const float* b2      = (const float*)d_in[7];
    float* out = (float*)d_out;

    char* ws = (char*)d_ws;
    int*      counts  = (int*)      (ws + 0);
    int*      bucket  = (int*)      (ws + 64);          // 512 KB
    float*    energy  = (float*)    (ws + 524352);      // 128 KB
    ushort_t* w1t     = (ushort_t*) (ws + 655424);      // 768 KB
    ushort_t* wht     = (ushort_t*) (ws + 1441856);     // 384 KB

    transpose_kernel<<<NE * 96 + NE * 48, 256, 0, stream>>>(W1, Wh, w1t, wht, counts);
    scatter_kernel<<<NATOMS / 256, 256, 0, stream>>>(species, counts, bucket);
    mlp_kernel<<<NGRID, 256, 0, stream>>>(rep, counts, bucket, w1t, wht,
                                          b1, bh, W2, b2, energy);
    reduce_kernel<<<NB, 256, 0, stream>>>(energy, out);
}

// Round 8
// 127.022 us; speedup vs baseline: 1.1187x; 1.1187x over previous
//
#include <hip/hip_runtime.h>

typedef __attribute__((ext_vector_type(8))) short bf16x8;
typedef __attribute__((ext_vector_type(4))) float f32x4;
typedef unsigned short ushort_t;

#define NB 32
#define NA 1024
#define NATOMS (NB*NA)
#define D  384
#define H1 256
#define H2 192
#define NE 4
#define TA 64
#define NGRID 515            // max sum of ceil(n_e/64)

__device__ __forceinline__ ushort_t f2bf(float f) {
    union { float f; unsigned u; } v; v.f = f;
    unsigned r = v.u + 0x7FFF + ((v.u >> 16) & 1);   // RNE
    return (ushort_t)(r >> 16);
}

// per-wave ballot histogram -> 4 atomics per block -> rank write
__global__ __launch_bounds__(256) void scatter_kernel(
    const int* __restrict__ species, int* __restrict__ counts, int* __restrict__ bucket)
{
    __shared__ int wcnt[4][4];
    __shared__ int wbase[4][4];
    const int t = threadIdx.x, lane = t & 63, wv = t >> 6;
    const int i = blockIdx.x * 256 + t;
    const int e = species[i];

    unsigned long long m0 = __ballot(e == 0);
    unsigned long long m1 = __ballot(e == 1);
    unsigned long long m2 = __ballot(e == 2);
    unsigned long long m3 = __ballot(e == 3);
    unsigned long long mym = (e == 0) ? m0 : (e == 1) ? m1 : (e == 2) ? m2 : m3;
    const unsigned long long lt = (lane == 63) ? 0x7FFFFFFFFFFFFFFFull
                                               : ((1ull << lane) - 1ull);
    const int rank = __popcll(mym & lt);

    if (lane == 0) {
        wcnt[wv][0] = __popcll(m0); wcnt[wv][1] = __popcll(m1);
        wcnt[wv][2] = __popcll(m2); wcnt[wv][3] = __popcll(m3);
    }
    __syncthreads();
    if (t < NE) {
        int s = t;
        int tot = wcnt[0][s] + wcnt[1][s] + wcnt[2][s] + wcnt[3][s];
        int b = atomicAdd(&counts[s], tot);
        for (int w = 0; w < 4; ++w) { wbase[w][s] = b; b += wcnt[w][s]; }
    }
    __syncthreads();
    bucket[(e << 15) + wbase[wv][e] + rank] = i;
}

// fused transpose+convert (W1 and Wh) + counts zeroing (runs BEFORE scatter)
__global__ __launch_bounds__(256) void transpose_kernel(
    const float* __restrict__ W1, const float* __restrict__ Wh,
    ushort_t* __restrict__ w1t, ushort_t* __restrict__ wht,
    int* __restrict__ counts)
{
    if (blockIdx.x == 0 && threadIdx.x < NE) counts[threadIdx.x] = 0;
    __shared__ float tile[32][33];
    const int t = threadIdx.x;
    int bid = blockIdx.x;
    const float* src; ushort_t* dst; int R, C, e, rt, ct;
    if (bid < NE * 96) {                       // W1: [384][256], 12x8 tiles
        e = bid / 96; int rem = bid % 96; rt = rem / 8; ct = rem % 8;
        src = W1; dst = w1t; R = D; C = H1;
    } else {                                   // Wh: [256][192], 8x6 tiles
        bid -= NE * 96;
        e = bid / 48; int rem = bid % 48; rt = rem / 6; ct = rem % 6;
        src = Wh; dst = wht; R = H1; C = H2;
    }
    const float* S  = src + ((size_t)e * R + rt * 32) * C + ct * 32;
    ushort_t*    Dp = dst + ((size_t)e * C + ct * 32) * R + rt * 32;
    {
        int row = t >> 3, c4 = (t & 7) * 4;
        float4 v = *(const float4*)(S + (size_t)row * C + c4);
        tile[row][c4 + 0] = v.x; tile[row][c4 + 1] = v.y;
        tile[row][c4 + 2] = v.z; tile[row][c4 + 3] = v.w;
    }
    __syncthreads();
    {
        int orow = t >> 3, k4 = (t & 7) * 4;
        ushort4 o;
        o.x = f2bf(tile[k4 + 0][orow]);
        o.y = f2bf(tile[k4 + 1][orow]);
        o.z = f2bf(tile[k4 + 2][orow]);
        o.w = f2bf(tile[k4 + 3][orow]);
        *(ushort4*)(Dp + (size_t)orow * R + k4) = o;
    }
}

// 512 threads / 8 waves; TA=64; XOR-swizzled LDS; H1t aliases Xt (phase order safe)
__global__ __launch_bounds__(512, 4) void mlp_kernel(
    const float*    __restrict__ rep,
    const int*      __restrict__ counts,
    const int*      __restrict__ bucket,
    const ushort_t* __restrict__ w1t,      // [E][H1][D]  bf16
    const ushort_t* __restrict__ wht,      // [E][H2][H1] bf16
    const float*    __restrict__ b1,
    const float*    __restrict__ bh,
    const float*    __restrict__ W2,
    const float*    __restrict__ b2,
    float*          __restrict__ energy)
{
    const int c0 = counts[0], c1 = counts[1], c2 = counts[2], c3 = counts[3];
    const int t0 = (c0 + 63) >> 6, t1 = (c1 + 63) >> 6, t2 = (c2 + 63) >> 6;
    const int t3 = (c3 + 63) >> 6;
    int bid = blockIdx.x;
    int e, tile, n;
    if      (bid < t0)                { e = 0; tile = bid;                n = c0; }
    else if (bid < t0 + t1)           { e = 1; tile = bid - t0;           n = c1; }
    else if (bid < t0 + t1 + t2)      { e = 2; tile = bid - t0 - t1;      n = c2; }
    else if (bid < t0 + t1 + t2 + t3) { e = 3; tile = bid - t0 - t1 - t2; n = c3; }
    else return;
    const int base = tile * TA;

    const int t    = threadIdx.x;
    const int lane = t & 63;
    const int wv   = t >> 6;        // 0..7
    const int g    = lane >> 4;
    const int r    = lane & 15;
    const int r7   = r & 7;

    __shared__ ushort_t smem[TA * D];          // 49,152 B
    ushort_t* Xt  = smem;                      // [64][384] swizzled
    ushort_t* H1t = smem;                      // [64][256] swizzled — ALIASES Xt
    float*    eparts = (float*)(smem + 20480); // 6*64 floats @ byte 40960 (above H1t's 32768)

    // ---- stage all of X (64 x 384) as bf16, swizzled; 512 threads, 1 row per 8
    {
        const int srow = t >> 3, scs = t & 7, sswz = srow & 7;
        int ai = base + srow;
        int gs = bucket[(e << 15) + (ai < n ? ai : base)];
        const float* xp = rep + (size_t)gs * D;
        #pragma unroll
        for (int i = 0; i < 6; ++i) {
            const int cs = scs + 8 * i;
            float4 v0 = *(const float4*)(xp + cs * 8);
            float4 v1 = *(const float4*)(xp + cs * 8 + 4);
            union { bf16x8 v; ushort_t u[8]; } pk;
            pk.u[0] = f2bf(v0.x); pk.u[1] = f2bf(v0.y);
            pk.u[2] = f2bf(v0.z); pk.u[3] = f2bf(v0.w);
            pk.u[4] = f2bf(v1.x); pk.u[5] = f2bf(v1.y);
            pk.u[6] = f2bf(v1.z); pk.u[7] = f2bf(v1.w);
            *(bf16x8*)(Xt + srow * D + ((cs ^ sswz) << 3)) = pk.v;
        }
    }
    __syncthreads();

    // ---- phase 1: C1^T; wave owns 32 h-cols (nn=0,1); A = W1 (global, prefetched)
    const ushort_t* a1p = w1t + ((size_t)e * H1 + wv * 32 + r) * D + g * 8;
    const int koff1 = (bid & 3) * 3;          // per-block K-order stagger

    f32x4 acc1[2][4];
    #pragma unroll
    for (int nn = 0; nn < 2; ++nn)
        #pragma unroll
        for (int m = 0; m < 4; ++m)
            acc1[nn][m] = (f32x4){0.f, 0.f, 0.f, 0.f};

    uint4 afc[2], afn[2];
    {
        int k0 = koff1 * 32;
        afc[0] = *(const uint4*)(a1p + k0);
        afc[1] = *(const uint4*)(a1p + 16 * D + k0);
    }
    for (int ks = 0; ks < 12; ++ks) {
        int kse = ks + koff1; if (kse >= 12) kse -= 12;
        if (ks < 11) {
            int ksn = kse + 1; if (ksn >= 12) ksn -= 12;
            afn[0] = *(const uint4*)(a1p + ksn * 32);
            afn[1] = *(const uint4*)(a1p + 16 * D + ksn * 32);
        }
        bf16x8 bx[4];
        #pragma unroll
        for (int m = 0; m < 4; ++m) {
            const int cs = kse * 4 + g;
            bx[m] = *(const bf16x8*)(Xt + (m * 16 + r) * D + ((cs ^ r7) << 3));
        }
        #pragma unroll
        for (int nn = 0; nn < 2; ++nn)
            #pragma unroll
            for (int m = 0; m < 4; ++m)
                acc1[nn][m] = __builtin_amdgcn_mfma_f32_16x16x32_bf16(
                    __builtin_bit_cast(bf16x8, afc[nn]), bx[m], acc1[nn][m], 0, 0, 0);
        afc[0] = afn[0]; afc[1] = afn[1];
    }
    __syncthreads();   // everyone done READING Xt; safe to overwrite with H1t

    // ---- +b1, pack, write H1t (swizzled, aliases Xt)
    #pragma unroll
    for (int nn = 0; nn < 2; ++nn) {
        float bv[4];
        #pragma unroll
        for (int q = 0; q < 4; ++q)
            bv[q] = b1[e * H1 + wv * 32 + nn * 16 + g * 4 + q];
        #pragma unroll
        for (int m = 0; m < 4; ++m) {
            unsigned p0 = f2bf(acc1[nn][m][0] + bv[0]);
            unsigned p1 = f2bf(acc1[nn][m][1] + bv[1]);
            unsigned p2 = f2bf(acc1[nn][m][2] + bv[2]);
            unsigned p3 = f2bf(acc1[nn][m][3] + bv[3]);
            uint2 pk; pk.x = p0 | (p1 << 16); pk.y = p2 | (p3 << 16);
            const int col = wv * 32 + nn * 16 + g * 4;
            const int cs  = col >> 3;
            const int phys = (m * 16 + r) * H1 + ((cs ^ r7) << 3) + (col & 7);
            *(uint2*)(H1t + phys) = pk;
        }
    }
    __syncthreads();

    // ---- phase 2: C2^T; waves 0..5 own 32 h2-cols each; A = Wh (global, prefetched)
    f32x4 acc2[2][4];
    #pragma unroll
    for (int nn = 0; nn < 2; ++nn)
        #pragma unroll
        for (int m = 0; m < 4; ++m)
            acc2[nn][m] = (f32x4){0.f, 0.f, 0.f, 0.f};

    if (wv < 6) {
        const ushort_t* a2p = wht + ((size_t)e * H2 + wv * 32 + r) * H1 + g * 8;
        const int koff2 = (bid & 3) * 2;
        uint4 af2c[2], af2n[2];
        {
            int k0 = koff2 * 32;
            af2c[0] = *(const uint4*)(a2p + k0);
            af2c[1] = *(const uint4*)(a2p + 16 * H1 + k0);
        }
        for (int ks = 0; ks < 8; ++ks) {
            int kse = ks + koff2; if (kse >= 8) kse -= 8;
            if (ks < 7) {
                int ksn = kse + 1; if (ksn >= 8) ksn -= 8;
                af2n[0] = *(const uint4*)(a2p + ksn * 32);
                af2n[1] = *(const uint4*)(a2p + 16 * H1 + ksn * 32);
            }
            bf16x8 bx[4];
            #pragma unroll
            for (int m = 0; m < 4; ++m) {
                const int cs = kse * 4 + g;
                bx[m] = *(const bf16x8*)(H1t + (m * 16 + r) * H1 + ((cs ^ r7) << 3));
            }
            #pragma unroll
            for (int nn = 0; nn < 2; ++nn)
                #pragma unroll
                for (int m = 0; m < 4; ++m)
                    acc2[nn][m] = __builtin_amdgcn_mfma_f32_16x16x32_bf16(
                        __builtin_bit_cast(bf16x8, af2c[nn]), bx[m], acc2[nn][m], 0, 0, 0);
            af2c[0] = af2n[0]; af2c[1] = af2n[1];
        }

        // epilogue part 1: relu(C2^T+bh)·W2, reduce this wave's 32 cols
        #pragma unroll
        for (int m = 0; m < 4; ++m) {
            float s = 0.f;
            #pragma unroll
            for (int nn = 0; nn < 2; ++nn) {
                float bhv[4], w2v[4];
                #pragma unroll
                for (int q = 0; q < 4; ++q) {
                    int h2i = e * H2 + wv * 32 + nn * 16 + g * 4 + q;
                    bhv[q] = bh[h2i];
                    w2v[q] = W2[h2i];
                }
                #pragma unroll
                for (int q = 0; q < 4; ++q) {
                    float z = acc2[nn][m][q] + bhv[q];
                    z = fmaxf(z, 0.f);
                    s += z * w2v[q];
                }
            }
            s += __shfl_xor(s, 16, 64);
            s += __shfl_xor(s, 32, 64);
            if (lane < 16) eparts[wv * TA + m * 16 + r] = s;
        }
    }
    __syncthreads();

    // epilogue part 2: combine 6 wave-partials, add b2, store per-atom energy
    if (t < TA) {
        int ai = base + t;
        if (ai < n) {
            int gi = bucket[(e << 15) + ai];
            float tot = b2[e];
            #pragma unroll
            for (int w = 0; w < 6; ++w) tot += eparts[w * TA + t];
            energy[gi] = tot;
        }
    }
}

__global__ void reduce_kernel(const float* __restrict__ energy, float* __restrict__ out) {
    const int b = blockIdx.x, t = threadIdx.x;
    float s = 0.f;
    for (int i = t; i < NA; i += 256) s += energy[b * NA + i];
    for (int off = 32; off > 0; off >>= 1) s += __shfl_down(s, off, 64);
    __shared__ float ws[4];
    if ((t & 63) == 0) ws[t >> 6] = s;
    __syncthreads();
    if (t == 0) out[b] = ws[0] + ws[1] + ws[2] + ws[3];
}

extern "C" void kernel_launch(void* const* d_in, const int* in_sizes, int n_in,
                              void* d_out, int out_size, void* d_ws, size_t ws_size,
                              hipStream_t stream) {
    const float* rep     = (const float*)d_in[0];
    const int*   species = (const int*)  d_in[1];
    const float* W1      = (const float*)d_in[2];
    const float* b1      = (const float*)d_in[3];
    const float* Wh      = (const float*)d_in[4];
    const float* bh      = (const float*)d_in[5];
    const float* W2      = (const float*)d_in[6];
    const float* b2      = (const float*)d_in[7];
    float* out = (float*)d_out;

    char* ws = (char*)d_ws;
    int*      counts  = (int*)      (ws + 0);
    int*      bucket  = (int*)      (ws + 64);          // 512 KB
    float*    energy  = (float*)    (ws + 524352);      // 128 KB
    ushort_t* w1t     = (ushort_t*) (ws + 655424);      // 768 KB
    ushort_t* wht     = (ushort_t*) (ws + 1441856);     // 384 KB

    transpose_kernel<<<NE * 96 + NE * 48, 256, 0, stream>>>(W1, Wh, w1t, wht, counts);
    scatter_kernel<<<NATOMS / 256, 256, 0, stream>>>(species, counts, bucket);
    mlp_kernel<<<NGRID, 512, 0, stream>>>(rep, counts, bucket, w1t, wht,
                                          b1, bh, W2, b2, energy);
    reduce_kernel<<<NB, 256, 0, stream>>>(energy, out);
}

// Round 9
// 126.797 us; speedup vs baseline: 1.1207x; 1.0018x over previous
//
#include <hip/hip_runtime.h>

typedef __attribute__((ext_vector_type(8))) short bf16x8;
typedef __attribute__((ext_vector_type(4))) float f32x4;
typedef unsigned short ushort_t;

#define NB 32
#define NA 1024
#define NATOMS (NB*NA)
#define D  384
#define H1 256
#define H2 192
#define NE 4
#define TA 64
#define NGRID 515            // max sum of ceil(n_e/64)

__device__ __forceinline__ ushort_t f2bf(float f) {
    union { float f; unsigned u; } v; v.f = f;
    unsigned r = v.u + 0x7FFF + ((v.u >> 16) & 1);   // RNE
    return (ushort_t)(r >> 16);
}

// per-wave ballot histogram -> 4 atomics per block -> rank write
__global__ __launch_bounds__(256) void scatter_kernel(
    const int* __restrict__ species, int* __restrict__ counts, int* __restrict__ bucket)
{
    __shared__ int wcnt[4][4];
    __shared__ int wbase[4][4];
    const int t = threadIdx.x, lane = t & 63, wv = t >> 6;
    const int i = blockIdx.x * 256 + t;
    const int e = species[i];

    unsigned long long m0 = __ballot(e == 0);
    unsigned long long m1 = __ballot(e == 1);
    unsigned long long m2 = __ballot(e == 2);
    unsigned long long m3 = __ballot(e == 3);
    unsigned long long mym = (e == 0) ? m0 : (e == 1) ? m1 : (e == 2) ? m2 : m3;
    const unsigned long long lt = (lane == 63) ? 0x7FFFFFFFFFFFFFFFull
                                               : ((1ull << lane) - 1ull);
    const int rank = __popcll(mym & lt);

    if (lane == 0) {
        wcnt[wv][0] = __popcll(m0); wcnt[wv][1] = __popcll(m1);
        wcnt[wv][2] = __popcll(m2); wcnt[wv][3] = __popcll(m3);
    }
    __syncthreads();
    if (t < NE) {
        int s = t;
        int tot = wcnt[0][s] + wcnt[1][s] + wcnt[2][s] + wcnt[3][s];
        int b = atomicAdd(&counts[s], tot);
        for (int w = 0; w < 4; ++w) { wbase[w][s] = b; b += wcnt[w][s]; }
    }
    __syncthreads();
    bucket[(e << 15) + wbase[wv][e] + rank] = i;
}

// fused transpose+convert (W1 and Wh) + counts zeroing (runs BEFORE scatter)
__global__ __launch_bounds__(256) void transpose_kernel(
    const float* __restrict__ W1, const float* __restrict__ Wh,
    ushort_t* __restrict__ w1t, ushort_t* __restrict__ wht,
    int* __restrict__ counts)
{
    if (blockIdx.x == 0 && threadIdx.x < NE) counts[threadIdx.x] = 0;
    __shared__ float tile[32][33];
    const int t = threadIdx.x;
    int bid = blockIdx.x;
    const float* src; ushort_t* dst; int R, C, e, rt, ct;
    if (bid < NE * 96) {                       // W1: [384][256], 12x8 tiles
        e = bid / 96; int rem = bid % 96; rt = rem / 8; ct = rem % 8;
        src = W1; dst = w1t; R = D; C = H1;
    } else {                                   // Wh: [256][192], 8x6 tiles
        bid -= NE * 96;
        e = bid / 48; int rem = bid % 48; rt = rem / 6; ct = rem % 6;
        src = Wh; dst = wht; R = H1; C = H2;
    }
    const float* S  = src + ((size_t)e * R + rt * 32) * C + ct * 32;
    ushort_t*    Dp = dst + ((size_t)e * C + ct * 32) * R + rt * 32;
    {
        int row = t >> 3, c4 = (t & 7) * 4;
        float4 v = *(const float4*)(S + (size_t)row * C + c4);
        tile[row][c4 + 0] = v.x; tile[row][c4 + 1] = v.y;
        tile[row][c4 + 2] = v.z; tile[row][c4 + 3] = v.w;
    }
    __syncthreads();
    {
        int orow = t >> 3, k4 = (t & 7) * 4;
        ushort4 o;
        o.x = f2bf(tile[k4 + 0][orow]);
        o.y = f2bf(tile[k4 + 1][orow]);
        o.z = f2bf(tile[k4 + 2][orow]);
        o.w = f2bf(tile[k4 + 3][orow]);
        *(ushort4*)(Dp + (size_t)orow * R + k4) = o;
    }
}

// 512 threads / 8 waves; TA=64; XOR-swizzled LDS; H1t aliases Xt;
// depth-4 static prefetch ring on weight fragments (fully unrolled K-loops)
__global__ __launch_bounds__(512, 4) void mlp_kernel(
    const float*    __restrict__ rep,
    const int*      __restrict__ counts,
    const int*      __restrict__ bucket,
    const ushort_t* __restrict__ w1t,      // [E][H1][D]  bf16
    const ushort_t* __restrict__ wht,      // [E][H2][H1] bf16
    const float*    __restrict__ b1,
    const float*    __restrict__ bh,
    const float*    __restrict__ W2,
    const float*    __restrict__ b2,
    float*          __restrict__ energy)
{
    const int c0 = counts[0], c1 = counts[1], c2 = counts[2], c3 = counts[3];
    const int t0 = (c0 + 63) >> 6, t1 = (c1 + 63) >> 6, t2 = (c2 + 63) >> 6;
    const int t3 = (c3 + 63) >> 6;
    int bid = blockIdx.x;
    int e, tile, n;
    if      (bid < t0)                { e = 0; tile = bid;                n = c0; }
    else if (bid < t0 + t1)           { e = 1; tile = bid - t0;           n = c1; }
    else if (bid < t0 + t1 + t2)      { e = 2; tile = bid - t0 - t1;      n = c2; }
    else if (bid < t0 + t1 + t2 + t3) { e = 3; tile = bid - t0 - t1 - t2; n = c3; }
    else return;
    const int base = tile * TA;

    const int t    = threadIdx.x;
    const int lane = t & 63;
    const int wv   = t >> 6;        // 0..7
    const int g    = lane >> 4;
    const int r    = lane & 15;
    const int r7   = r & 15 & 7;

    __shared__ ushort_t smem[TA * D];          // 49,152 B
    ushort_t* Xt  = smem;                      // [64][384] swizzled
    ushort_t* H1t = smem;                      // [64][256] swizzled — ALIASES Xt
    float*    eparts = (float*)(smem + 20480); // bytes 40960.. (above H1t's 32768)

    const int koff1 = (bid & 3) * 3;          // per-block K-order stagger
    const int koff2 = (bid & 3) * 2;
    const ushort_t* a1p = w1t + ((size_t)e * H1 + wv * 32 + r) * D + g * 8;
    const ushort_t* a2p = wht + ((size_t)e * H2 + wv * 32 + r) * H1 + g * 8;

    // ---- phase-1 weight prologue: depth-4 ring, issued BEFORE staging barrier
    uint4 af[4][2];
    #pragma unroll
    for (int p = 0; p < 4; ++p) {
        int kse = p + koff1; if (kse >= 12) kse -= 12;
        af[p][0] = *(const uint4*)(a1p + kse * 32);
        af[p][1] = *(const uint4*)(a1p + 16 * D + kse * 32);
    }

    // ---- stage all of X (64 x 384) as bf16, swizzled; 512 threads, 1 row per 8
    {
        const int srow = t >> 3, scs = t & 7, sswz = srow & 7;
        int ai = base + srow;
        int gs = bucket[(e << 15) + (ai < n ? ai : base)];
        const float* xp = rep + (size_t)gs * D;
        #pragma unroll
        for (int i = 0; i < 6; ++i) {
            const int cs = scs + 8 * i;
            float4 v0 = *(const float4*)(xp + cs * 8);
            float4 v1 = *(const float4*)(xp + cs * 8 + 4);
            union { bf16x8 v; ushort_t u[8]; } pk;
            pk.u[0] = f2bf(v0.x); pk.u[1] = f2bf(v0.y);
            pk.u[2] = f2bf(v0.z); pk.u[3] = f2bf(v0.w);
            pk.u[4] = f2bf(v1.x); pk.u[5] = f2bf(v1.y);
            pk.u[6] = f2bf(v1.z); pk.u[7] = f2bf(v1.w);
            *(bf16x8*)(Xt + srow * D + ((cs ^ sswz) << 3)) = pk.v;
        }
    }
    __syncthreads();

    // ---- phase 1: C1^T; wave owns 32 h-cols; fully unrolled, ring prefetch
    f32x4 acc1[2][4];
    #pragma unroll
    for (int nn = 0; nn < 2; ++nn)
        #pragma unroll
        for (int m = 0; m < 4; ++m)
            acc1[nn][m] = (f32x4){0.f, 0.f, 0.f, 0.f};

    #pragma unroll
    for (int ks = 0; ks < 12; ++ks) {
        int kse = ks + koff1; if (kse >= 12) kse -= 12;
        bf16x8 bx[4];
        #pragma unroll
        for (int m = 0; m < 4; ++m) {
            const int cs = kse * 4 + g;
            bx[m] = *(const bf16x8*)(Xt + (m * 16 + r) * D + ((cs ^ r7) << 3));
        }
        #pragma unroll
        for (int nn = 0; nn < 2; ++nn)
            #pragma unroll
            for (int m = 0; m < 4; ++m)
                acc1[nn][m] = __builtin_amdgcn_mfma_f32_16x16x32_bf16(
                    __builtin_bit_cast(bf16x8, af[ks & 3][nn]), bx[m], acc1[nn][m], 0, 0, 0);
        if (ks + 4 < 12) {
            int ksn = ks + 4 + koff1; if (ksn >= 12) ksn -= 12;
            af[ks & 3][0] = *(const uint4*)(a1p + ksn * 32);
            af[ks & 3][1] = *(const uint4*)(a1p + 16 * D + ksn * 32);
        }
    }
    __syncthreads();   // all waves done READING Xt; safe to overwrite with H1t

    // ---- phase-2 weight prologue: issue now, hides under H1t pack/write + barrier
    uint4 af2[4][2];
    if (wv < 6) {
        #pragma unroll
        for (int p = 0; p < 4; ++p) {
            int kse = p + koff2; if (kse >= 8) kse -= 8;
            af2[p][0] = *(const uint4*)(a2p + kse * 32);
            af2[p][1] = *(const uint4*)(a2p + 16 * H1 + kse * 32);
        }
    }

    // ---- +b1, pack, write H1t (swizzled, aliases Xt)
    #pragma unroll
    for (int nn = 0; nn < 2; ++nn) {
        float bv[4];
        #pragma unroll
        for (int q = 0; q < 4; ++q)
            bv[q] = b1[e * H1 + wv * 32 + nn * 16 + g * 4 + q];
        #pragma unroll
        for (int m = 0; m < 4; ++m) {
            unsigned p0 = f2bf(acc1[nn][m][0] + bv[0]);
            unsigned p1 = f2bf(acc1[nn][m][1] + bv[1]);
            unsigned p2 = f2bf(acc1[nn][m][2] + bv[2]);
            unsigned p3 = f2bf(acc1[nn][m][3] + bv[3]);
            uint2 pk; pk.x = p0 | (p1 << 16); pk.y = p2 | (p3 << 16);
            const int col = wv * 32 + nn * 16 + g * 4;
            const int cs  = col >> 3;
            const int phys = (m * 16 + r) * H1 + ((cs ^ r7) << 3) + (col & 7);
            *(uint2*)(H1t + phys) = pk;
        }
    }
    __syncthreads();

    // ---- phase 2: C2^T; waves 0..5 own 32 h2-cols; fully unrolled, ring prefetch
    f32x4 acc2[2][4];
    #pragma unroll
    for (int nn = 0; nn < 2; ++nn)
        #pragma unroll
        for (int m = 0; m < 4; ++m)
            acc2[nn][m] = (f32x4){0.f, 0.f, 0.f, 0.f};

    if (wv < 6) {
        #pragma unroll
        for (int ks = 0; ks < 8; ++ks) {
            int kse = ks + koff2; if (kse >= 8) kse -= 8;
            bf16x8 bx[4];
            #pragma unroll
            for (int m = 0; m < 4; ++m) {
                const int cs = kse * 4 + g;
                bx[m] = *(const bf16x8*)(H1t + (m * 16 + r) * H1 + ((cs ^ r7) << 3));
            }
            #pragma unroll
            for (int nn = 0; nn < 2; ++nn)
                #pragma unroll
                for (int m = 0; m < 4; ++m)
                    acc2[nn][m] = __builtin_amdgcn_mfma_f32_16x16x32_bf16(
                        __builtin_bit_cast(bf16x8, af2[ks & 3][nn]), bx[m], acc2[nn][m], 0, 0, 0);
            if (ks + 4 < 8) {
                int ksn = ks + 4 + koff2; if (ksn >= 8) ksn -= 8;
                af2[ks & 3][0] = *(const uint4*)(a2p + ksn * 32);
                af2[ks & 3][1] = *(const uint4*)(a2p + 16 * H1 + ksn * 32);
            }
        }

        // epilogue part 1: relu(C2^T+bh)·W2, reduce this wave's 32 cols
        #pragma unroll
        for (int m = 0; m < 4; ++m) {
            float s = 0.f;
            #pragma unroll
            for (int nn = 0; nn < 2; ++nn) {
                float bhv[4], w2v[4];
                #pragma unroll
                for (int q = 0; q < 4; ++q) {
                    int h2i = e * H2 + wv * 32 + nn * 16 + g * 4 + q;
                    bhv[q] = bh[h2i];
                    w2v[q] = W2[h2i];
                }
                #pragma unroll
                for (int q = 0; q < 4; ++q) {
                    float z = acc2[nn][m][q] + bhv[q];
                    z = fmaxf(z, 0.f);
                    s += z * w2v[q];
                }
            }
            s += __shfl_xor(s, 16, 64);
            s += __shfl_xor(s, 32, 64);
            if (lane < 16) eparts[wv * TA + m * 16 + r] = s;
        }
    }
    __syncthreads();

    // epilogue part 2: combine 6 wave-partials, add b2, store per-atom energy
    if (t < TA) {
        int ai = base + t;
        if (ai < n) {
            int gi = bucket[(e << 15) + ai];
            float tot = b2[e];
            #pragma unroll
            for (int w = 0; w < 6; ++w) tot += eparts[w * TA + t];
            energy[gi] = tot;
        }
    }
}

__global__ void reduce_kernel(const float* __restrict__ energy, float* __restrict__ out) {
    const int b = blockIdx.x, t = threadIdx.x;
    float s = 0.f;
    for (int i = t; i < NA; i += 256) s += energy[b * NA + i];
    for (int off = 32; off > 0; off >>= 1) s += __shfl_down(s, off, 64);
    __shared__ float ws[4];
    if ((t & 63) == 0) ws[t >> 6] = s;
    __syncthreads();
    if (t == 0) out[b] = ws[0] + ws[1] + ws[2] + ws[3];
}

extern "C" void kernel_launch(void* const* d_in, const int* in_sizes, int n_in,
                              void* d_out, int out_size, void* d_ws, size_t ws_size,
                              hipStream_t stream) {
    const float* rep     = (const float*)d_in[0];
    const int*   species = (const int*)  d_in[1];
    const float* W1      = (const float*)d_in[2];
    const float* b1      = (const float*)d_in[3];
    const float* Wh      = (const float*)d_in[4];
    const float* bh      = (const float*)d_in[5];
    const float* W2      = (const float*)d_in[6];
    const float* b2      = (const float*)d_in[7];
    float* out = (float*)d_out;

    char* ws = (char*)d_ws;
    int*      counts  = (int*)      (ws + 0);
    int*      bucket  = (int*)      (ws + 64);          // 512 KB
    float*    energy  = (float*)    (ws + 524352);      // 128 KB
    ushort_t* w1t     = (ushort_t*) (ws + 655424);      // 768 KB
    ushort_t* wht     = (ushort_t*) (ws + 1441856);     // 384 KB

    transpose_kernel<<<NE * 96 + NE * 48, 256, 0, stream>>>(W1, Wh, w1t, wht, counts);
    scatter_kernel<<<NATOMS / 256, 256, 0, stream>>>(species, counts, bucket);
    mlp_kernel<<<NGRID, 512, 0, stream>>>(rep, counts, bucket, w1t, wht,
                                          b1, bh, W2, b2, energy);
    reduce_kernel<<<NB, 256, 0, stream>>>(energy, out);
}